// Round 4
// baseline (48302.090 us; speedup 1.0000x reference)
//
#include <hip/hip_runtime.h>
#include <hip/hip_bf16.h>

// RecurrentQNet: B=64, S=1024, D=64, H=512, A=16
// R4: persistent cooperative recurrence kernel (2 grid barriers/step).
//  - FIX: pred partial accumulation uses __hip_atomic_fetch_add(AGENT)
//    (was unsafeAtomicAdd — unscoped, suspect cross-XCD lost updates).
//  - FIX: barrier words on a private cacheline (cnt@+0B, gen@+128B),
//    predbuf moved to +256B (was sharing cnt's 128B line).
//  - HEDGE: hipLaunchCooperativeKernel return checked; fallback = R2-proven
//    multi-launch path (pred feedback via cb_preds output slot).
// Outputs: q[64,1024,16], cb_preds[64,1024,64], hidden[1,64,512], ca1[64,1024,512]

#define B_ 64
#define S_ 1024
#define D_ 64
#define H_ 512
#define A_ 16
#define NWG 256

__device__ __forceinline__ float afload(const float* p) {
  return __hip_atomic_load(p, __ATOMIC_RELAXED, __HIP_MEMORY_SCOPE_AGENT);
}
__device__ __forceinline__ void afstore(float* p, float v) {
  __hip_atomic_store(p, v, __ATOMIC_RELAXED, __HIP_MEMORY_SCOPE_AGENT);
}

// sense-reversing grid barrier; cnt = bar[0], gen = bar[32] (separate 128B lines)
__device__ __forceinline__ void gridbar(int* cnt, int* gen) {
  __syncthreads();
  if (threadIdx.x == 0) {
    int g = __hip_atomic_load(gen, __ATOMIC_RELAXED, __HIP_MEMORY_SCOPE_AGENT);
    int old = __hip_atomic_fetch_add(cnt, 1, __ATOMIC_ACQ_REL, __HIP_MEMORY_SCOPE_AGENT);
    if (old == NWG - 1) {
      __hip_atomic_store(cnt, 0, __ATOMIC_RELAXED, __HIP_MEMORY_SCOPE_AGENT);
      __hip_atomic_fetch_add(gen, 1, __ATOMIC_RELEASE, __HIP_MEMORY_SCOPE_AGENT);
    } else {
      while (__hip_atomic_load(gen, __ATOMIC_ACQUIRE, __HIP_MEMORY_SCOPE_AGENT) == g)
        __builtin_amdgcn_s_sleep(2);
    }
  }
  __syncthreads();
}

// Persistent recurrence. Grid 256 WGs x 256 thr, 1 WG/CU (cooperative).
// WG = (bblk 0..7)*(jblk 0..31): 8 batches x 16 h-cols.
// Phase 1 threads: jl = tid>>4 (16 h-cols), ks = tid&15 (K-slice of 11 f4).
//   in-row per b: [x 16f4 | pred 16f4 | pad 12f4 | h 128f4 | pad], stride 177 f4.
//   ks 0..3 = i-region (f4<44), ks 4..15 = h-region -> gi/gh separable in shfl tree.
// Phase 2 threads: colp = tid>>5 (8, 2 u-cols each), ks2 = tid&31.
__global__ __launch_bounds__(256, 1) void k_recurrent(
    const float* __restrict__ x,      // [64,1024,64]
    const float* __restrict__ W_ih,   // [1536,128]
    const float* __restrict__ W_hh,   // [1536,512]
    const float* __restrict__ b_ih,   // [1536]
    const float* __restrict__ b_hh,   // [1536]
    const float* __restrict__ cb_w1,  // [512,512]
    const float* __restrict__ cb_b1,  // [512]
    const float* __restrict__ cb_w2,  // [64,512]
    const float* __restrict__ cb_b2,  // [64]
    float* __restrict__ hist,         // [64,1024,512] h history (= ca1 slot)
    float* __restrict__ hidden,       // [64,512]
    float* __restrict__ predbuf,      // [2][64*64] ping-pong (pre-bias sums)
    int* __restrict__ bar)            // cnt@[0], gen@[32]
{
  __shared__ __align__(16) float s_in[8 * 708];
  __shared__ __align__(16) float s_h2[8 * 516];
  __shared__ float s_w2[64 * 17];
  __shared__ float s_u[8 * 17];

  const int tid = threadIdx.x;
  const int wg = blockIdx.x;
  const int bblk = wg >> 5;         // 0..7
  const int jblk = wg & 31;         // 0..31
  const int b0 = bblk * 8;
  const int j0 = jblk * 16;

  for (int i = tid; i < 8 * 708; i += 256) s_in[i] = 0.f;   // pads stay 0 forever
  for (int i = tid; i < 64 * 16; i += 256) {
    int d = i >> 4, k = i & 15;
    s_w2[d * 17 + k] = cb_w2[(size_t)d * H_ + j0 + k];
  }

  // phase-1 weights into registers (persist across all 1024 steps)
  const int jl = tid >> 4, ks = tid & 15;
  const int j = j0 + jl;
  float4 w[3][11];
#pragma unroll
  for (int g = 0; g < 3; ++g)
#pragma unroll
    for (int m = 0; m < 11; ++m) {
      int f4 = ks * 11 + m;
      float4 v = make_float4(0.f, 0.f, 0.f, 0.f);
      if (f4 < 32)                       // i-region: [x|pred] cols of W_ih
        v = *(const float4*)(W_ih + (size_t)(g * H_ + j) * 128 + f4 * 4);
      else if (f4 >= 44 && f4 < 172)     // h-region: W_hh
        v = *(const float4*)(W_hh + (size_t)(g * H_ + j) * H_ + (f4 - 44) * 4);
      w[g][m] = v;
    }
  const float bi0 = b_ih[0 * H_ + j], bi1 = b_ih[1 * H_ + j], bi2 = b_ih[2 * H_ + j];
  const float bh0 = b_hh[0 * H_ + j], bh1 = b_hh[1 * H_ + j], bh2 = b_hh[2 * H_ + j];
  const int colp = tid >> 5, ks2 = tid & 31;
  const float cb1v0 = cb_b1[j0 + colp * 2 + 0];
  const float cb1v1 = cb_b1[j0 + colp * 2 + 1];

  int* cnt = bar;
  int* gen = bar + 32;
  const int lane = tid & 63;
  const int base = lane & 48;
  float4* s_in4 = (float4*)s_in;
  float4* s_h24 = (float4*)s_h2;

  __syncthreads();

  for (int t = 0; t < S_; ++t) {
    const float* predc = predbuf + (t & 1) * (B_ * D_);
    float* predn = predbuf + ((t + 1) & 1) * (B_ * D_);

    // ---- phase 1 staging ----
    for (int i = tid; i < 128; i += 256) {          // x_t: 8b x 16 f4
      int b = i >> 4, f = i & 15;
      s_in4[b * 177 + f] = *(const float4*)(x + ((size_t)(b0 + b) * S_ + t) * D_ + f * 4);
    }
    for (int i = tid; i < 512; i += 256) {          // pred_{t-1} (+cb_b2): 8b x 64
      int b = i >> 6, d = i & 63;
      float v = 0.f;
      if (t > 0) v = afload(predc + (b0 + b) * 64 + d) + cb_b2[d];
      s_in[b * 708 + 64 + d] = v;
    }
    for (int i = tid; i < 4096; i += 256) {         // h_{t-1}: 8b x 512
      int b = i >> 9, k = i & 511;
      float v = 0.f;
      if (t > 0) v = afload(hist + ((size_t)(b0 + b) * S_ + (t - 1)) * H_ + k);
      s_in[b * 708 + 176 + k] = v;
    }
    if (jblk == 0) {                                // zero next pred accumulator
      for (int i = tid; i < 512; i += 256)
        afstore(predn + b0 * 64 + i, 0.f);
    }
    __syncthreads();

    // ---- phase 1 compute: gates ----
    float acc[8][3];
#pragma unroll
    for (int b = 0; b < 8; ++b)
#pragma unroll
      for (int g = 0; g < 3; ++g) acc[b][g] = 0.f;

#pragma unroll
    for (int b = 0; b < 8; ++b) {
      float4 a[11];
#pragma unroll
      for (int m = 0; m < 11; ++m) a[m] = s_in4[b * 177 + ks * 11 + m];
#pragma unroll
      for (int m = 0; m < 11; ++m) {
#pragma unroll
        for (int g = 0; g < 3; ++g) {
          acc[b][g] += a[m].x * w[g][m].x + a[m].y * w[g][m].y +
                       a[m].z * w[g][m].z + a[m].w * w[g][m].w;
        }
      }
    }

    // reduce over 16 K-slices; ks 0..3 = i-part, 4..15 = h-part
#pragma unroll
    for (int b = 0; b < 8; ++b) {
      float gi[3], gh[3];
#pragma unroll
      for (int g = 0; g < 3; ++g) {
        float v = acc[b][g];
        v += __shfl_xor(v, 1);
        v += __shfl_xor(v, 2);
        float a0  = __shfl(v, base + 0);
        float a4  = __shfl(v, base + 4);
        float a8  = __shfl(v, base + 8);
        float a12 = __shfl(v, base + 12);
        gi[g] = a0;
        gh[g] = a4 + a8 + a12;
      }
      float hprev = s_in[b * 708 + 176 + j];
      float r = 1.f / (1.f + __expf(-(gi[0] + bi0 + gh[0] + bh0)));
      float z = 1.f / (1.f + __expf(-(gi[1] + bi1 + gh[1] + bh1)));
      float n = tanhf(gi[2] + bi2 + r * (gh[2] + bh2));
      float hnew = (1.f - z) * n + z * hprev;
      if (ks == 0) {
        afstore(hist + ((size_t)(b0 + b) * S_ + t) * H_ + j, hnew);
        if (t == S_ - 1) hidden[(b0 + b) * H_ + j] = hnew;
      }
    }

    if (t == S_ - 1) break;        // no feedback needed after last step
    gridbar(cnt, gen);

    // ---- phase 2: u = relu(cb_w1 @ h_t + b1) on WG's 16 cols + pred partials ----
    for (int i = tid; i < 4096; i += 256) {
      int b = i >> 9, k = i & 511;
      s_h2[b * 516 + k] = afload(hist + ((size_t)(b0 + b) * S_ + t) * H_ + k);
    }
    __syncthreads();

    float ua0[8], ua1[8];
#pragma unroll
    for (int b = 0; b < 8; ++b) { ua0[b] = 0.f; ua1[b] = 0.f; }
#pragma unroll
    for (int m = 0; m < 4; ++m) {
      int k4 = ks2 + 32 * m;
      float4 w0 = *(const float4*)(cb_w1 + (size_t)(j0 + colp * 2 + 0) * H_ + k4 * 4);
      float4 w1 = *(const float4*)(cb_w1 + (size_t)(j0 + colp * 2 + 1) * H_ + k4 * 4);
#pragma unroll
      for (int b = 0; b < 8; ++b) {
        float4 hv = s_h24[b * 129 + k4];
        ua0[b] += hv.x * w0.x + hv.y * w0.y + hv.z * w0.z + hv.w * w0.w;
        ua1[b] += hv.x * w1.x + hv.y * w1.y + hv.z * w1.z + hv.w * w1.w;
      }
    }
#pragma unroll
    for (int b = 0; b < 8; ++b) {
      float v0 = ua0[b], v1 = ua1[b];
      v0 += __shfl_xor(v0, 1);  v1 += __shfl_xor(v1, 1);
      v0 += __shfl_xor(v0, 2);  v1 += __shfl_xor(v1, 2);
      v0 += __shfl_xor(v0, 4);  v1 += __shfl_xor(v1, 4);
      v0 += __shfl_xor(v0, 8);  v1 += __shfl_xor(v1, 8);
      v0 += __shfl_xor(v0, 16); v1 += __shfl_xor(v1, 16);
      ua0[b] = v0; ua1[b] = v1;
    }
    if (ks2 == 0) {
#pragma unroll
      for (int b = 0; b < 8; ++b) {
        s_u[b * 17 + colp * 2 + 0] = fmaxf(ua0[b] + cb1v0, 0.f);
        s_u[b * 17 + colp * 2 + 1] = fmaxf(ua1[b] + cb1v1, 0.f);
      }
    }
    __syncthreads();

    // pred partials over this WG's 16 u-cols -> AGENT-scoped atomic accumulate
#pragma unroll
    for (int q = 0; q < 2; ++q) {
      int o = tid * 2 + q;
      int b = o >> 6, d = o & 63;
      float p = 0.f;
#pragma unroll
      for (int k = 0; k < 16; ++k) p += s_w2[d * 17 + k] * s_u[b * 17 + k];
      __hip_atomic_fetch_add(predn + (b0 + b) * 64 + d, p,
                             __ATOMIC_RELAXED, __HIP_MEMORY_SCOPE_AGENT);
    }
    gridbar(cnt, gen);
  }
}

// ================= fallback path (R2-proven multi-launch) =================
// k_gru_step: grid 128 WGs x 256 thr; pred feedback read from cb_preds slot.
__global__ __launch_bounds__(256) void k_gru_step(
    int t,
    const float* __restrict__ x, const float* __restrict__ W_ih,
    const float* __restrict__ W_hh, const float* __restrict__ b_ih,
    const float* __restrict__ b_hh,
    const float* __restrict__ cbp,   // [64,1024,64] pred history
    float* __restrict__ hist, float* __restrict__ hidden)
{
    __shared__ __align__(16) float s_in[64 * 132];
    __shared__ __align__(16) float s_w[3 * 4 * 132];

    const int tid = threadIdx.x;
    const int b = tid >> 2;
    const int jj = tid & 3;
    const int j0 = blockIdx.x * 4;
    const int j = j0 + jj;

    float gi0 = 0.f, gi1 = 0.f, gi2 = 0.f;
    float gh0 = 0.f, gh1 = 0.f, gh2 = 0.f;

    for (int i = tid; i < 1024; i += 256) {
        int bb = i >> 4, f = i & 15;
        *(float4*)(s_in + bb * 132 + f * 4) =
            *(const float4*)(x + ((size_t)bb * S_ + t) * D_ + f * 4);
    }
    for (int i = tid; i < 1024; i += 256) {
        int bb = i >> 4, f = i & 15;
        float4 v = make_float4(0.f, 0.f, 0.f, 0.f);
        if (t > 0) v = *(const float4*)(cbp + ((size_t)bb * S_ + (t - 1)) * D_ + f * 4);
        *(float4*)(s_in + bb * 132 + 64 + f * 4) = v;
    }
    for (int i = tid; i < 384; i += 256) {
        int g = i >> 7, rem = i & 127, wj = rem >> 5, f = rem & 31;
        *(float4*)(s_w + (g * 4 + wj) * 132 + f * 4) =
            *(const float4*)(W_ih + (size_t)(g * 512 + j0 + wj) * 128 + f * 4);
    }
    __syncthreads();
    {
        const float4* arow = (const float4*)(s_in + b * 132);
        const float4* w0 = (const float4*)(s_w + (0 * 4 + jj) * 132);
        const float4* w1 = (const float4*)(s_w + (1 * 4 + jj) * 132);
        const float4* w2 = (const float4*)(s_w + (2 * 4 + jj) * 132);
#pragma unroll 8
        for (int k4 = 0; k4 < 32; ++k4) {
            float4 a = arow[k4];
            float4 u = w0[k4]; gi0 += a.x * u.x + a.y * u.y + a.z * u.z + a.w * u.w;
            float4 v = w1[k4]; gi1 += a.x * v.x + a.y * v.y + a.z * v.z + a.w * v.w;
            float4 w = w2[k4]; gi2 += a.x * w.x + a.y * w.y + a.z * w.z + a.w * w.w;
        }
    }

    float hprev = 0.f;
    if (t > 0) {
        for (int c = 0; c < 4; ++c) {
            __syncthreads();
            for (int i = tid; i < 2048; i += 256) {
                int bb = i >> 5, f = i & 31;
                *(float4*)(s_in + bb * 132 + f * 4) =
                    *(const float4*)(hist + ((size_t)bb * S_ + (t - 1)) * H_ + c * 128 + f * 4);
            }
            for (int i = tid; i < 384; i += 256) {
                int g = i >> 7, rem = i & 127, wj = rem >> 5, f = rem & 31;
                *(float4*)(s_w + (g * 4 + wj) * 132 + f * 4) =
                    *(const float4*)(W_hh + (size_t)(g * 512 + j0 + wj) * 512 + c * 128 + f * 4);
            }
            __syncthreads();
            const float4* arow = (const float4*)(s_in + b * 132);
            const float4* w0 = (const float4*)(s_w + (0 * 4 + jj) * 132);
            const float4* w1 = (const float4*)(s_w + (1 * 4 + jj) * 132);
            const float4* w2 = (const float4*)(s_w + (2 * 4 + jj) * 132);
#pragma unroll 8
            for (int k4 = 0; k4 < 32; ++k4) {
                float4 a = arow[k4];
                float4 u = w0[k4]; gh0 += a.x * u.x + a.y * u.y + a.z * u.z + a.w * u.w;
                float4 v = w1[k4]; gh1 += a.x * v.x + a.y * v.y + a.z * v.z + a.w * v.w;
                float4 w = w2[k4]; gh2 += a.x * w.x + a.y * w.y + a.z * w.z + a.w * w.w;
            }
        }
        hprev = hist[((size_t)b * S_ + (t - 1)) * H_ + j];
    }

    float r = 1.f / (1.f + __expf(-(gi0 + b_ih[j] + gh0 + b_hh[j])));
    float z = 1.f / (1.f + __expf(-(gi1 + b_ih[512 + j] + gh1 + b_hh[512 + j])));
    float n = tanhf(gi2 + b_ih[1024 + j] + r * (gh2 + b_hh[1024 + j]));
    float hnew = (1.f - z) * n + z * hprev;

    hist[((size_t)b * S_ + t) * H_ + j] = hnew;
    if (t == S_ - 1) hidden[b * H_ + j] = hnew;
}

__global__ __launch_bounds__(256) void k_u(
    int t, const float* __restrict__ cb_w1, const float* __restrict__ cb_b1,
    const float* __restrict__ hist, float* __restrict__ u_ws)
{
    __shared__ __align__(16) float s_in[64 * 132];
    __shared__ __align__(16) float s_w[4 * 132];
    const int tid = threadIdx.x;
    const int b = tid >> 2;
    const int jj = tid & 3;
    const int j0 = blockIdx.x * 4;
    const int j = j0 + jj;

    float acc = 0.f;
    for (int c = 0; c < 4; ++c) {
        if (c) __syncthreads();
        for (int i = tid; i < 2048; i += 256) {
            int bb = i >> 5, f = i & 31;
            *(float4*)(s_in + bb * 132 + f * 4) =
                *(const float4*)(hist + ((size_t)bb * S_ + t) * H_ + c * 128 + f * 4);
        }
        if (tid < 128) {
            int wj = tid >> 5, f = tid & 31;
            *(float4*)(s_w + wj * 132 + f * 4) =
                *(const float4*)(cb_w1 + (size_t)(j0 + wj) * 512 + c * 128 + f * 4);
        }
        __syncthreads();
        const float4* arow = (const float4*)(s_in + b * 132);
        const float4* wr = (const float4*)(s_w + jj * 132);
#pragma unroll 8
        for (int k4 = 0; k4 < 32; ++k4) {
            float4 a = arow[k4];
            float4 w = wr[k4];
            acc += a.x * w.x + a.y * w.y + a.z * w.z + a.w * w.w;
        }
    }
    u_ws[b * H_ + j] = fmaxf(acc + cb_b1[j], 0.f);
}

__global__ __launch_bounds__(256) void k_pred(
    int t, const float* __restrict__ cb_w2, const float* __restrict__ cb_b2,
    const float* __restrict__ u_ws, float* __restrict__ cb_preds)
{
    __shared__ __align__(16) float s_in[64 * 132];
    __shared__ __align__(16) float s_w[4 * 132];
    const int tid = threadIdx.x;
    const int b = tid >> 2;
    const int jj = tid & 3;
    const int d0 = blockIdx.x * 4;
    const int d = d0 + jj;

    float acc = 0.f;
    for (int c = 0; c < 4; ++c) {
        if (c) __syncthreads();
        for (int i = tid; i < 2048; i += 256) {
            int bb = i >> 5, f = i & 31;
            *(float4*)(s_in + bb * 132 + f * 4) =
                *(const float4*)(u_ws + (size_t)bb * H_ + c * 128 + f * 4);
        }
        if (tid < 128) {
            int wj = tid >> 5, f = tid & 31;
            *(float4*)(s_w + wj * 132 + f * 4) =
                *(const float4*)(cb_w2 + (size_t)(d0 + wj) * 512 + c * 128 + f * 4);
        }
        __syncthreads();
        const float4* arow = (const float4*)(s_in + b * 132);
        const float4* wr = (const float4*)(s_w + jj * 132);
#pragma unroll 8
        for (int k4 = 0; k4 < 32; ++k4) {
            float4 a = arow[k4];
            float4 w = wr[k4];
            acc += a.x * w.x + a.y * w.y + a.z * w.z + a.w * w.w;
        }
    }
    cb_preds[((size_t)b * S_ + t) * D_ + d] = acc + cb_b2[d];
}

// ================= epilogue (shared by both paths) =================
__global__ __launch_bounds__(256) void k_up_epi(
    const float* __restrict__ hist,
    const float* __restrict__ cb_w1, const float* __restrict__ cb_b1,
    const float* __restrict__ cb_w2, const float* __restrict__ cb_b2,
    float* __restrict__ cb_preds)
{
  __shared__ __align__(16) float s_a[16 * 516];
  const int tid = threadIdx.x;
  const int r = tid & 15, cset = tid >> 4;
  const int row0 = blockIdx.x * 16;

  for (int i = tid; i < 2048; i += 256) {
    int rr = i >> 7, f = i & 127;
    *(float4*)(s_a + rr * 516 + f * 4) = *(const float4*)(hist + (size_t)(row0 + rr) * H_ + f * 4);
  }
  __syncthreads();

  float acc[32];
#pragma unroll
  for (int jj = 0; jj < 32; ++jj) acc[jj] = 0.f;
  const float4* arow = (const float4*)(s_a + r * 516);
  for (int k4 = 0; k4 < 128; ++k4) {
    float4 a = arow[k4];
#pragma unroll
    for (int jj = 0; jj < 32; ++jj) {
      int jc = cset + (jj << 4);
      float4 wv = *(const float4*)(cb_w1 + (size_t)jc * H_ + k4 * 4);
      acc[jj] += a.x * wv.x + a.y * wv.y + a.z * wv.z + a.w * wv.w;
    }
  }
  __syncthreads();
#pragma unroll
  for (int jj = 0; jj < 32; ++jj) {
    int jc = cset + (jj << 4);
    s_a[r * 516 + jc] = fmaxf(acc[jj] + cb_b1[jc], 0.f);
  }
  __syncthreads();

#pragma unroll
  for (int q = 0; q < 4; ++q) {
    int d = cset + (q << 4);
    float p = cb_b2[d];
    const float4* urow = (const float4*)(s_a + r * 516);
    for (int k4 = 0; k4 < 128; ++k4) {
      float4 u = urow[k4];
      float4 wv = *(const float4*)(cb_w2 + (size_t)d * H_ + k4 * 4);
      p += u.x * wv.x + u.y * wv.y + u.z * wv.z + u.w * wv.w;
    }
    cb_preds[(size_t)(row0 + r) * D_ + d] = p;
  }
}

__global__ __launch_bounds__(256) void k_fc_inplace(
    float* __restrict__ hist, const float* __restrict__ fc_w, const float* __restrict__ fc_b)
{
  __shared__ __align__(16) float s_a[16 * 516];
  const int tid = threadIdx.x;
  const int r = tid & 15;
  const int jset = tid >> 4;
  const int row0 = blockIdx.x * 16;

  for (int i = tid; i < 2048; i += 256) {
    int rr = i >> 7, f = i & 127;
    *(float4*)(s_a + rr * 516 + f * 4) = *(const float4*)(hist + (size_t)(row0 + rr) * H_ + f * 4);
  }
  __syncthreads();

  float acc[32];
#pragma unroll
  for (int jj = 0; jj < 32; ++jj) acc[jj] = 0.f;
  const float4* arow = (const float4*)(s_a + r * 516);
  for (int k4 = 0; k4 < 128; ++k4) {
    float4 a = arow[k4];
#pragma unroll
    for (int jj = 0; jj < 32; ++jj) {
      int jc = jset + (jj << 4);
      float4 wv = *(const float4*)(fc_w + (size_t)jc * H_ + k4 * 4);
      acc[jj] += a.x * wv.x + a.y * wv.y + a.z * wv.z + a.w * wv.w;
    }
  }
  float* crow = hist + (size_t)(row0 + r) * H_;
#pragma unroll
  for (int jj = 0; jj < 32; ++jj) {
    int jc = jset + (jj << 4);
    crow[jc] = fmaxf(acc[jj] + fc_b[jc], 0.f);
  }
}

__global__ __launch_bounds__(256) void k_q(
    const float* __restrict__ ca1, const float* __restrict__ out_w,
    const float* __restrict__ out_b, float* __restrict__ q)
{
  __shared__ __align__(16) float s_a[16 * 516];
  __shared__ __align__(16) float s_w[16 * 516];
  const int tid = threadIdx.x;
  const int r = tid >> 4;
  const int a_ = tid & 15;
  const int row0 = blockIdx.x * 16;

  for (int i = tid; i < 2048; i += 256) {
    int rr = i >> 7, f = i & 127;
    *(float4*)(s_a + rr * 516 + f * 4) = *(const float4*)(ca1 + (size_t)(row0 + rr) * H_ + f * 4);
  }
  for (int i = tid; i < 2048; i += 256) {
    int rr = i >> 7, f = i & 127;
    *(float4*)(s_w + rr * 516 + f * 4) = *(const float4*)(out_w + (size_t)rr * H_ + f * 4);
  }
  __syncthreads();

  const float4* arow = (const float4*)(s_a + r * 516);
  const float4* wrow = (const float4*)(s_w + a_ * 516);
  float acc = 0.f;
#pragma unroll 8
  for (int k4 = 0; k4 < 128; ++k4) {
    float4 a = arow[k4];
    float4 wv = wrow[k4];
    acc += a.x * wv.x + a.y * wv.y + a.z * wv.z + a.w * wv.w;
  }
  q[(size_t)(row0 + r) * A_ + a_] = acc + out_b[a_];
}

// ---------------- host ----------------
extern "C" void kernel_launch(void* const* d_in, const int* in_sizes, int n_in,
                              void* d_out, int out_size, void* d_ws, size_t ws_size,
                              hipStream_t stream) {
  const float* x     = (const float*)d_in[0];
  const float* W_ih  = (const float*)d_in[1];
  const float* W_hh  = (const float*)d_in[2];
  const float* b_ih  = (const float*)d_in[3];
  const float* b_hh  = (const float*)d_in[4];
  const float* fc_w  = (const float*)d_in[5];
  const float* fc_b  = (const float*)d_in[6];
  const float* out_w = (const float*)d_in[7];
  const float* out_b = (const float*)d_in[8];
  const float* cb_w1 = (const float*)d_in[9];
  const float* cb_b1 = (const float*)d_in[10];
  const float* cb_w2 = (const float*)d_in[11];
  const float* cb_b2 = (const float*)d_in[12];

  float* q_out  = (float*)d_out;                     // [64,1024,16]
  float* cbp    = q_out + (size_t)B_ * S_ * A_;      // [64,1024,64]
  float* hidden = cbp + (size_t)B_ * S_ * D_;        // [1,64,512]
  float* ca1    = hidden + (size_t)B_ * H_;          // [64,1024,512] h-history then ca1

  int*   bar     = (int*)d_ws;                       // cnt@[0], gen@[32]
  float* predbuf = (float*)d_ws + 64;                // persistent: [2][4096]
  float* u_ws    = (float*)d_ws + 64;                // fallback:   [64*512] (disjoint use)

  hipMemsetAsync(d_ws, 0, 256, stream);

  void* args[] = { (void*)&x, (void*)&W_ih, (void*)&W_hh, (void*)&b_ih, (void*)&b_hh,
                   (void*)&cb_w1, (void*)&cb_b1, (void*)&cb_w2, (void*)&cb_b2,
                   (void*)&ca1, (void*)&hidden, (void*)&predbuf, (void*)&bar };
  hipError_t cerr = hipLaunchCooperativeKernel((const void*)k_recurrent,
                                               dim3(NWG), dim3(256), args, 0, stream);
  if (cerr != hipSuccess) {
    // R2-proven fallback (slow but correct): diagnostic for coop-launch failure
    for (int t = 0; t < S_; ++t) {
      k_gru_step<<<128, 256, 0, stream>>>(t, x, W_ih, W_hh, b_ih, b_hh, cbp, ca1, hidden);
      k_u<<<128, 256, 0, stream>>>(t, cb_w1, cb_b1, ca1, u_ws);
      k_pred<<<16, 256, 0, stream>>>(t, cb_w2, cb_b2, u_ws, cbp);
    }
  }

  k_up_epi<<<4096, 256, 0, stream>>>(ca1, cb_w1, cb_b1, cb_w2, cb_b2, cbp);
  k_fc_inplace<<<4096, 256, 0, stream>>>(ca1, fc_w, fc_b);
  k_q<<<4096, 256, 0, stream>>>(ca1, out_w, out_b, q_out);
}